// Round 12
// baseline (1101.329 us; speedup 1.0000x reference)
//
#include <hip/hip_runtime.h>

// ---------------------------------------------------------------------------
// TiLISTA: M=512, N=2048, B=8192, T=5 — i8 dual-plane GEMMs, fp32 z/x state.
//   x0 = mu0 * y @ A                      (fp32 in d_out)
//   for t=1..5:
//     r = x @ A^T - y        (fp32 in ws -> per-row i8 planes)
//     z = x - mu_t * (r @ A) (x REPLAYED bit-exactly from z_{t-1}+thr+beta
//                             inside the epilogue; z written in place)
//     x = shrink(z,beta,k)   (planes for next GEMM + thr row; fp32 only t=5)
// GEMM operands: per-row q = q1*128 + q0 (|q|<=16256, ~15 bits of rowmax).
// 3 x mfma_i32_16x16x64_i8 per 64-K: a1b1->accH, a1b0+a0b1->accM;
// v = sA*sB*(accH*16384 + accM*128).
// Grid flat-swizzle: m-block = flat%64 (R6).
// R9: GEMM schedule: LDS dbuf + prefetch-before-compute, raw s_barrier +
//   counted s_waitcnt vmcnt(L), XOR-swizzled tiles, s_setprio around MFMA.
// R10 PM: 2-rows/wave shrink REGRESSED (occupancy halved). Reverted.
// R11: shrink: ballot counting + uniform early exit (exact same top-k set).
// R12 PM: NJ=2 big GEMM REGRESSED (staging overhead/FLOP doubled).
// R13 PM: FAILED. z from dequantized x planes -> tie-flip blowup.
//   RULE: z needs bit-exact x.
// R14 PM: replay epilogue reading outF through its own pointer ->
//   aliasing-serialized epilogue (45->66us).
// R15: Zprev via separate const __restrict__ -> bit-exact, 48us.
// R16: 8-wave 512-thread big-GEMM block: occupancy 18.5->32%, 48->45us.
// R17: LDS-transposed epilogue (coalesced float4 I/O): 45->42us. BEST: 710us.
// R18/R19 PM: XCD remap of shrink/rowquant sped THEM up but slowed big
//   GEMMs 42->56us (undefined block->XCD mapping mis-placed Zprev L2 lines;
//   latency not BW — traffic identical). 8-wave r-GEMM isolated at +2us vs
//   4-wave (R19 vs R17 at equal big-GEMM times). BOTH reverted -> R17 config.
//   RULES: no locality schemes on unverified dispatch->XCD models; re-anchor
//   attribution when a bundled change partially reverts.
// R20: epilogue-operand register prefetch (T14 issue-early/use-late). The
//   42us big GEMM = ~25us latency-bound K-loop (HBM near-idle) + ~17us
//   serial epilogue burst (Zprev 64MB read + z 64MB write @2.7TB/s). Zprev/
//   thr (and Yaux in EPI1) are K-loop-independent: load them into registers
//   BEFORE stage(0,0), pinned with sched_barrier(0) so the compiler cannot
//   sink them; they retire under the first-tile latency wait. WAR-safe:
//   each block reads only the tile it alone later writes. +40 VGPR (~104,
//   under the 128 cap of launch_bounds(512,4)).
// shrink = exact k-th-largest |z| via binary search on float bits.
// ---------------------------------------------------------------------------

typedef int int4v __attribute__((ext_vector_type(4)));

__device__ __forceinline__ void quant2(float v, float inv_s,
                                       signed char& q1, signed char& q0) {
    int q = __float2int_rn(v * inv_s);
    q = q > 16256 ? 16256 : (q < -16256 ? -16256 : q);
    int hi = (q + 64) >> 7;            // round-half-up -> [-127,127]
    q1 = (signed char)hi;
    q0 = (signed char)(q - (hi << 7)); // [-64,63]
}

__device__ __forceinline__ void gl_lds16(const signed char* g, signed char* lds) {
    __builtin_amdgcn_global_load_lds(
        (const __attribute__((address_space(1))) void*)g,
        (__attribute__((address_space(3))) void*)lds, 16, 0, 0);
}

// out[m][n] = epilogue( sum_k Aop[m][k]*Bop[k][n] ); Bop in B^T layout [n][k].
// Block tile 128 x BN; WM x WN waves of 64 lanes (NTHR = WM*WN*64).
// EPI 0: outF = mu * v                   (x0; A=y planes, B=AT planes)
// EPI 1: outF = v - Yaux                 (r;  A=x planes, B=A planes)
// EPI 2: outF = replay(Zprev) - mu * v   (z;  A=r planes, B=AT planes;
//         replay(z) = |z|>=thr ? z : copysign(max(|z|-betaPrev,0), z))
template<int BN, int WM, int WN, int EPI>
__global__ __launch_bounds__(WM * WN * 64, (WM * WN == 8) ? 4 : 2)
void gemm_i8(
    const signed char* __restrict__ A1, const signed char* __restrict__ A0, int lda,
    const signed char* __restrict__ B1, const signed char* __restrict__ B0, int ldb,
    const float* __restrict__ sAv,   // per-row scale of A-operand
    const float* __restrict__ sBv,   // per-row scale of B-operand (per out col)
    const float* __restrict__ Yaux,  // EPI1: y fp32
    const float* __restrict__ Zprev, // EPI2: z_{t-1} fp32 (= outF buffer)
    const float* __restrict__ thrv,  // EPI2: per-row shrink threshold (t-1)
    const float* __restrict__ bPrev, // EPI2: &beta[t-1]
    float* __restrict__ outF,
    const float* __restrict__ muPtr, int muIdx, int K, int ldOut)
{
    constexpr int NTHR = WM * WN * 64;
    constexpr int MI   = 128 / WM / 16;   // m-frags per wave
    constexpr int NJf  = BN / WN / 16;    // n-frags per wave
    constexpr int AR   = 512 / NTHR;      // A 16B-chunk iters per plane
    constexpr int BR   = (BN * 4) / NTHR; // B 16B-chunk iters per plane
    constexpr int LPT  = 2 * (AR + BR);   // gl_lds loads per tile per thread
    constexpr int ASZ  = 128 * 64;        // one A staging buffer (bytes)
    constexpr int BSZ  = BN * 64;         // one B staging buffer (bytes)
    constexpr int C4   = BN / 4;          // float4 per tile row
    constexpr int PASS = (128 * C4) / NTHR;

    // staging buffers; after the K-loop, reused as fp32 epi tile [128][BN]
    __shared__ signed char smem[4 * ASZ + 4 * BSZ];
    signed char* const As1p = smem;                       // [2][ASZ]
    signed char* const As0p = smem + 2 * ASZ;             // [2][ASZ]
    signed char* const Bs1p = smem + 4 * ASZ;             // [2][BSZ]
    signed char* const Bs0p = smem + 4 * ASZ + 2 * BSZ;   // [2][BSZ]

    const int tid  = threadIdx.x;
    const int wid  = tid >> 6;
    const int lane = tid & 63;
    const int quad = lane >> 4;
    const int l16  = lane & 15;
    const int waveM = (wid / WN) * (MI * 16);
    const int waveN = (wid % WN) * (NJf * 16);
    const int swz   = (l16 >> 1) & 3;          // read-side XOR (rows: base%16==0)

    const int flat  = blockIdx.x + gridDim.x * blockIdx.y;
    const int mBase = (flat & 63) * 128;
    const int nBase = (flat >> 6) * BN;

    // R20: prefetch epilogue operands NOW — their HBM latency retires under
    // the K-loop's first-tile wait instead of serializing at the tail.
    // WAR-safe: this block reads only the tile it alone writes, read-first.
    float4 pfAux[PASS];
    float  pfThr[PASS];
    if constexpr (EPI == 1) {
        #pragma unroll
        for (int p = 0; p < PASS; ++p) {
            const int e = p * NTHR + tid;
            const size_t idx = (size_t)(mBase + e / C4) * ldOut
                             + nBase + (e % C4) * 4;
            pfAux[p] = *(const float4*)&Yaux[idx];
        }
    } else if constexpr (EPI == 2) {
        #pragma unroll
        for (int p = 0; p < PASS; ++p) {
            const int e  = p * NTHR + tid;
            const int gr = mBase + e / C4;
            const size_t idx = (size_t)gr * ldOut + nBase + (e % C4) * 4;
            pfAux[p] = *(const float4*)&Zprev[idx];
            pfThr[p] = thrv[gr];
        }
    }
    __builtin_amdgcn_sched_barrier(0);  // pin: prefetch issues before staging

    int4v accH[MI][NJf] = {};
    int4v accM[MI][NJf] = {};

    // Stage one 64-K tile into buffer b. LDS dest linear (global_load_lds
    // requirement); the global SOURCE chunk is XOR-swizzled so that the
    // ds_read below, applying the same XOR, sees logical chunk order.
    auto stage = [&](int b, int k0) {
        #pragma unroll
        for (int rr = 0; rr < AR; ++rr) {
            int c   = rr * NTHR + tid;         // 16B chunk id
            int row = c >> 2;
            int js  = (c & 3) ^ ((row >> 1) & 3);
            size_t ga = (size_t)(mBase + row) * lda + k0 + js * 16;
            size_t doff = (size_t)(b * ASZ + (rr * NTHR + wid * 64) * 16);
            gl_lds16(A1 + ga, As1p + doff);
            gl_lds16(A0 + ga, As0p + doff);
        }
        #pragma unroll
        for (int rr = 0; rr < BR; ++rr) {
            int c   = rr * NTHR + tid;
            int row = c >> 2;
            int js  = (c & 3) ^ ((row >> 1) & 3);
            size_t gb = (size_t)(nBase + row) * ldb + k0 + js * 16;
            size_t doff = (size_t)(b * BSZ + (rr * NTHR + wid * 64) * 16);
            gl_lds16(B1 + gb, Bs1p + doff);
            gl_lds16(B0 + gb, Bs0p + doff);
        }
    };

    const int KT = K >> 6;
    stage(0, 0);

    for (int kt = 0; kt < KT; ++kt) {
        const int cur = kt & 1;
        if (kt + 1 < KT) {
            stage(cur ^ 1, (kt + 1) << 6);
            // wait tile-kt's loads only; tile-(kt+1)'s LPT stay in flight
            // (prefetch loads are oldest and retire with the first wait)
            if constexpr (LPT == 4)      asm volatile("s_waitcnt vmcnt(4)" ::: "memory");
            else if constexpr (LPT == 6) asm volatile("s_waitcnt vmcnt(6)" ::: "memory");
            else                         asm volatile("s_waitcnt vmcnt(8)" ::: "memory");
        } else {
            asm volatile("s_waitcnt vmcnt(0)" ::: "memory");
        }
        __builtin_amdgcn_s_barrier();          // raw: no vmcnt drain

        int4v a1[MI], a0[MI], b1[NJf], b0[NJf];
        #pragma unroll
        for (int i = 0; i < MI; ++i) {
            int off = (waveM + i * 16 + l16) * 64 + ((quad ^ swz) * 16);
            a1[i] = *(const int4v*)(As1p + cur * ASZ + off);
            a0[i] = *(const int4v*)(As0p + cur * ASZ + off);
        }
        #pragma unroll
        for (int j = 0; j < NJf; ++j) {
            int off = (waveN + j * 16 + l16) * 64 + ((quad ^ swz) * 16);
            b1[j] = *(const int4v*)(Bs1p + cur * BSZ + off);
            b0[j] = *(const int4v*)(Bs0p + cur * BSZ + off);
        }
        __builtin_amdgcn_s_setprio(1);
        #pragma unroll
        for (int i = 0; i < MI; ++i)
            #pragma unroll
            for (int j = 0; j < NJf; ++j) {
                accH[i][j] = __builtin_amdgcn_mfma_i32_16x16x64_i8(a1[i], b1[j], accH[i][j], 0, 0, 0);
                accM[i][j] = __builtin_amdgcn_mfma_i32_16x16x64_i8(a1[i], b0[j], accM[i][j], 0, 0, 0);
                accM[i][j] = __builtin_amdgcn_mfma_i32_16x16x64_i8(a0[i], b1[j], accM[i][j], 0, 0, 0);
            }
        __builtin_amdgcn_s_setprio(0);
        __builtin_amdgcn_s_barrier();          // reads of buf[cur] done before
                                               // next iter's stage overwrites it
    }

    // ---- epilogue: acc -> LDS tile (fragment layout), then coalesced
    //      float4 global I/O (R17). Same per-element fp32 ops -> bit-exact.
    const float mu = muPtr[muIdx];
    const float betaPrev = (EPI == 2) ? bPrev[0] : 0.f;
    float* const epi = (float*)smem;           // [128][BN]

    #pragma unroll
    for (int i = 0; i < MI; ++i) {
        #pragma unroll
        for (int j = 0; j < NJf; ++j) {
            const int lr0 = waveM + i * 16 + quad * 4;
            const int lc  = waveN + j * 16 + l16;
            const float sB = sBv[nBase + lc];
            #pragma unroll
            for (int r2 = 0; r2 < 4; ++r2) {
                const int lr = lr0 + r2;
                const float sA = sAv[mBase + lr];
                epi[lr * BN + lc] = sA * sB *
                    ((float)accH[i][j][r2] * 16384.f
                   + (float)accM[i][j][r2] * 128.f);
            }
        }
    }
    __syncthreads();

    #pragma unroll
    for (int p = 0; p < PASS; ++p) {
        const int e  = p * NTHR + tid;
        const int lr = e / C4;
        const int c4 = e % C4;
        const int gr = mBase + lr;
        const size_t idx = (size_t)gr * ldOut + nBase + c4 * 4;
        const float4 v4 = *(const float4*)&epi[lr * BN + c4 * 4];
        float4 o;
        if constexpr (EPI == 0) {
            o.x = mu * v4.x; o.y = mu * v4.y;
            o.z = mu * v4.z; o.w = mu * v4.w;
        } else if constexpr (EPI == 1) {
            const float4 ya = pfAux[p];
            o.x = v4.x - ya.x; o.y = v4.y - ya.y;
            o.z = v4.z - ya.z; o.w = v4.w - ya.w;
        } else {
            const float4 zp = pfAux[p];
            const unsigned tb = __float_as_uint(pfThr[p]);
            const float zc[4] = {zp.x, zp.y, zp.z, zp.w};
            const float vc[4] = {v4.x, v4.y, v4.z, v4.w};
            float oc[4];
            #pragma unroll
            for (int k4 = 0; k4 < 4; ++k4) {
                // bit-exact shrink replay of z_{t-1} (same ops as
                // shrink_kernel: uint-bit compare, fmaxf, copysignf)
                const unsigned ab = __float_as_uint(fabsf(zc[k4]));
                float xv;
                if (ab >= tb) {
                    xv = zc[k4];
                } else {
                    xv = copysignf(
                        fmaxf(__uint_as_float(ab) - betaPrev, 0.f), zc[k4]);
                }
                oc[k4] = xv - mu * vc[k4];
            }
            o.x = oc[0]; o.y = oc[1]; o.z = oc[2]; o.w = oc[3];
        }
        *(float4*)&outF[idx] = o;
    }
}

// per-row quantization of a fp32 matrix to i8 dual planes + row scale
template<int COLS>
__global__ __launch_bounds__(256) void rowquant_kernel(
    const float* __restrict__ src,
    signed char* __restrict__ q1, signed char* __restrict__ q0,
    float* __restrict__ scale)
{
    const int wid  = threadIdx.x >> 6;
    const int lane = threadIdx.x & 63;
    const long long row = (long long)blockIdx.x * 4 + wid;
    constexpr int EP = COLS / 256;   // float4 per lane
    const float* s = src + row * COLS;

    float v[EP * 4];
    #pragma unroll
    for (int c = 0; c < EP; ++c) {
        float4 f = ((const float4*)s)[c * 64 + lane];
        v[c * 4 + 0] = f.x; v[c * 4 + 1] = f.y; v[c * 4 + 2] = f.z; v[c * 4 + 3] = f.w;
    }
    float mx = 0.f;
    #pragma unroll
    for (int i = 0; i < EP * 4; ++i) mx = fmaxf(mx, fabsf(v[i]));
    #pragma unroll
    for (int off = 32; off >= 1; off >>= 1) mx = fmaxf(mx, __shfl_xor(mx, off, 64));
    mx = fmaxf(mx, 1e-20f);
    if (lane == 0) scale[row] = mx / 16256.f;
    const float inv = 16256.f / mx;

    #pragma unroll
    for (int c = 0; c < EP; ++c) {
        size_t col = (size_t)(c * 64 + lane) * 4;
        signed char h[4], l[4];
        #pragma unroll
        for (int e = 0; e < 4; ++e) quant2(v[c * 4 + e], inv, h[e], l[e]);
        *(char4*)(q1 + row * COLS + col) = *(char4*)h;
        *(char4*)(q0 + row * COLS + col) = *(char4*)l;
    }
}

// R11/R14: one wave per row of z[.,2048]: exact k-th-largest |z| hard/soft
// threshold via scalar binary search on float bits with ballot counting +
// uniform early exit. Publishes per-row thr (for the next z-GEMM's exact
// replay), quantizes x -> i8 planes + scale (writePlanes), optionally
// writes x fp32 (writeF32, final iteration only).
__global__ __launch_bounds__(256) void shrink_kernel(
    float* __restrict__ z,
    signed char* __restrict__ X1, signed char* __restrict__ X0,
    float* __restrict__ sX, float* __restrict__ thrOut,
    const float* __restrict__ betaPtr, int tIdx, int kSel,
    int writeF32, int writePlanes)
{
    const int wid  = threadIdx.x >> 6;
    const int lane = threadIdx.x & 63;
    const long long row = (long long)blockIdx.x * 4 + wid;
    float* zr = z + row * 2048;

    float v[32];
    #pragma unroll
    for (int c = 0; c < 8; ++c) {
        float4 f = ((const float4*)zr)[c * 64 + lane];
        v[c * 4 + 0] = f.x; v[c * 4 + 1] = f.y; v[c * 4 + 2] = f.z; v[c * 4 + 3] = f.w;
    }

    if (kSel > 0) {
        const float beta = betaPtr[tIdx];
        unsigned a[32];
        #pragma unroll
        for (int i = 0; i < 32; ++i) a[i] = __float_as_uint(fabsf(v[i]));

        // invariant: cnt(>=lo) >= k, cnt(>=hi) < k. Early exit: any mid
        // with cnt(>=mid)==k classifies exactly the top-k set (identical
        // to thr = k-th largest); a tie straddling k makes cnt==k
        // unreachable -> loop runs to convergence (thr = v_k), also exact.
        unsigned lo = 0u, hi = 0x7F800000u;
        #pragma unroll 1
        for (int it = 0; it < 31; ++it) {
            const unsigned mid = (lo + hi) >> 1;
            int cnt = 0;
            #pragma unroll
            for (int i = 0; i < 32; ++i)
                cnt += (int)__popcll(__ballot(a[i] >= mid));
            if (cnt >= kSel) {
                lo = mid;
                if (cnt == kSel) break;
            } else {
                hi = mid;
            }
        }
        const unsigned thr = lo;
        if (lane == 0) thrOut[row] = __uint_as_float(thr);
        #pragma unroll
        for (int i = 0; i < 32; ++i) {
            if (a[i] < thr) {
                float av   = __uint_as_float(a[i]);
                float soft = fmaxf(av - beta, 0.f);
                v[i] = copysignf(soft, v[i]);
            }
        }
    } else {
        // no thresholding this step: replay must be identity -> thr = 0
        if (lane == 0) thrOut[row] = 0.f;
    }

    float mx = 0.f;
    #pragma unroll
    for (int i = 0; i < 32; ++i) mx = fmaxf(mx, fabsf(v[i]));
    #pragma unroll
    for (int off = 32; off >= 1; off >>= 1) mx = fmaxf(mx, __shfl_xor(mx, off, 64));
    mx = fmaxf(mx, 1e-20f);
    if (writePlanes && lane == 0) sX[row] = mx / 16256.f;
    const float inv = 16256.f / mx;

    #pragma unroll
    for (int c = 0; c < 8; ++c) {
        size_t col = (size_t)(c * 64 + lane) * 4;
        if (writePlanes) {
            signed char h[4], l[4];
            #pragma unroll
            for (int e = 0; e < 4; ++e) quant2(v[c * 4 + e], inv, h[e], l[e]);
            *(char4*)(X1 + row * 2048 + col) = *(char4*)h;
            *(char4*)(X0 + row * 2048 + col) = *(char4*)l;
        }
        if (writeF32) {
            float4 f;
            f.x = v[c * 4 + 0]; f.y = v[c * 4 + 1]; f.z = v[c * 4 + 2]; f.w = v[c * 4 + 3];
            ((float4*)zr)[c * 64 + lane] = f;
        }
    }
}

extern "C" void kernel_launch(void* const* d_in, const int* in_sizes, int n_in,
                              void* d_out, int out_size, void* d_ws, size_t ws_size,
                              hipStream_t stream)
{
    const float* y    = (const float*)d_in[0];   // [8192,512]
    const float* A    = (const float*)d_in[1];   // [512,2048]
    const float* W    = (const float*)d_in[2];   // [2048,512] == A^T
    const float* beta = (const float*)d_in[3];   // [6]
    const float* mu   = (const float*)d_in[4];   // [6]
    float* out = (float*)d_out;                  // x / z fp32, in place

    // workspace (~68 MB)
    signed char* A1q  = (signed char*)d_ws;          // [512][2048]
    signed char* A0q  = A1q  + 512 * 2048;
    signed char* AT1q = A0q  + 512 * 2048;           // [2048][512]
    signed char* AT0q = AT1q + 2048 * 512;
    signed char* y1q  = AT0q + 2048 * 512;           // [8192][512]
    signed char* y0q  = y1q  + 8192 * 512;
    signed char* x1q  = y0q  + 8192 * 512;           // [8192][2048]
    signed char* x0q  = x1q  + (size_t)8192 * 2048;
    signed char* r1q  = x0q  + (size_t)8192 * 2048;  // [8192][512]
    signed char* r0q  = r1q  + 8192 * 512;
    float* rF  = (float*)(r0q + 8192 * 512);         // [8192][512] fp32
    float* sa  = rF + (size_t)8192 * 512;            // [512]
    float* sat = sa  + 512;                          // [2048]
    float* sy  = sat + 2048;                         // [8192]
    float* sx  = sy  + 8192;                         // [8192]
    float* sr  = sx  + 8192;                         // [8192]
    float* thr = sr  + 8192;                         // [8192]

    rowquant_kernel<2048><<<128, 256, 0, stream>>>(A, A1q, A0q, sa);
    rowquant_kernel<512><<<512, 256, 0, stream>>>(W, AT1q, AT0q, sat);
    rowquant_kernel<512><<<2048, 256, 0, stream>>>(y, y1q, y0q, sy);

    // x0 = mu0 * y @ A  -> d_out fp32   (A-op = y planes, B-op = AT planes)
    gemm_i8<128, 4, 2, 0><<<dim3(16, 64), 512, 0, stream>>>(
        y1q, y0q, 512, AT1q, AT0q, 512, sy, sat,
        nullptr, nullptr, nullptr, nullptr, out, mu, 0, 512, 2048);
    // quantize x0 for GEMM use; thr=0 so the t=1 replay is identity
    shrink_kernel<<<2048, 256, 0, stream>>>(out, x1q, x0q, sx, thr, beta,
                                            0, 0, 0, 1);

    for (int t = 1; t <= 5; ++t) {
        double p = 0.012 * t; if (p > 0.12) p = 0.12;
        int kSel = (int)(p * 2048.0);   // 24,49,73,98,122

        // r = x @ A^T - y  -> rF fp32   (A-op = x planes, B-op = A planes)
        // R17 shape restored (4-wave 256-thr; 8-wave isolated at +2us)
        gemm_i8<64, 2, 2, 1><<<dim3(8, 64), 256, 0, stream>>>(
            x1q, x0q, 2048, A1q, A0q, 2048, sx, sa,
            y, nullptr, nullptr, nullptr, rF, mu, t, 2048, 512);
        // quantize r per-row
        rowquant_kernel<512><<<2048, 256, 0, stream>>>(rF, r1q, r0q, sr);

        // z = replay(z_{t-1}) - mu_t * (r @ A)  in place over d_out
        // (Zprev = out read via const __restrict__, R15's measured-fast form)
        gemm_i8<128, 4, 2, 2><<<dim3(16, 64), 512, 0, stream>>>(
            r1q, r0q, 512, AT1q, AT0q, 512, sr, sat,
            nullptr, out, thr, beta + (t - 1), out, mu, t, 512, 2048);

        // x = shrink(z): t<5 -> planes+thr only; t=5 -> fp32 output only
        shrink_kernel<<<2048, 256, 0, stream>>>(out, x1q, x0q, sx, thr, beta,
                                                t, kSel, t == 5 ? 1 : 0,
                                                t < 5 ? 1 : 0);
    }
}

// Round 13
// 692.246 us; speedup vs baseline: 1.5910x; 1.5910x over previous
//
#include <hip/hip_runtime.h>

// ---------------------------------------------------------------------------
// TiLISTA: M=512, N=2048, B=8192, T=5 — i8 dual-plane GEMMs, fp32 z/x state.
//   x0 = mu0 * y @ A                      (fp32 in d_out)
//   for t=1..5:
//     r = x @ A^T - y        (fp32 in ws -> per-row i8 planes)
//     z = x - mu_t * (r @ A) (x REPLAYED bit-exactly from z_{t-1}+thr+beta
//                             inside the epilogue; z written in place)
//     x = shrink(z,beta,k)   (planes for next GEMM + thr row; fp32 only t=5)
// GEMM operands: per-row q = q1*128 + q0 (|q|<=16256, ~15 bits of rowmax).
// 3 x mfma_i32_16x16x64_i8 per 64-K: a1b1->accH, a1b0+a0b1->accM;
// v = sA*sB*(accH*16384 + accM*128).
// Grid flat-swizzle: m-block = flat%64 (R6).
// R9: GEMM schedule: LDS dbuf + prefetch-before-compute, raw s_barrier +
//   counted s_waitcnt vmcnt(L), XOR-swizzled tiles, s_setprio around MFMA.
// R10 PM: 2-rows/wave shrink REGRESSED (occupancy halved). Reverted.
// R11: shrink: ballot counting + uniform early exit (exact same top-k set).
// R12 PM: NJ=2 big GEMM REGRESSED (staging overhead/FLOP doubled).
// R13 PM: FAILED. z from dequantized x planes -> tie-flip blowup.
//   RULE: z needs bit-exact x.
// R14 PM: replay epilogue reading outF through its own pointer ->
//   aliasing-serialized epilogue (45->66us).
// R15: Zprev via separate const __restrict__ -> bit-exact, 48us.
// R16: 8-wave 512-thread big-GEMM block: occupancy 18.5->32%, 48->45us.
// R17: LDS-transposed epilogue (coalesced float4 I/O): 45->42us. BEST: 710us.
// R18/R19 PM: XCD remap of shrink/rowquant slowed big GEMMs 42->56us
//   (undefined block->XCD mapping; latency not BW). 8-wave r-GEMM isolated
//   at +2us. Both reverted.
// R20 PM: register prefetch of epilogue operands at kernel entry SPILLED
//   under the launch_bounds(512,4) 128-reg cap (acc+frags+staging live):
//   WRITE 65->212MB, FETCH 47->119MB (scratch round-trips), 42->126us.
//   RULE: budget reg prefetch against the cap at MAX liveness; spills show
//   as FETCH/WRITE inflation even when VGPR_Count looks small.
// R21: exact R17 restore (best measured 710.5us). K-loop barrier-phase
//   latency is the residual (~3000cy/k-step vs ~400cy issue work); epilogue
//   loads are already latency-covered by 16 waves/CU x 8 independent
//   float4/thread. Further gains need a phase-split interleave (T3).
// shrink = exact k-th-largest |z| via binary search on float bits.
// ---------------------------------------------------------------------------

typedef int int4v __attribute__((ext_vector_type(4)));

__device__ __forceinline__ void quant2(float v, float inv_s,
                                       signed char& q1, signed char& q0) {
    int q = __float2int_rn(v * inv_s);
    q = q > 16256 ? 16256 : (q < -16256 ? -16256 : q);
    int hi = (q + 64) >> 7;            // round-half-up -> [-127,127]
    q1 = (signed char)hi;
    q0 = (signed char)(q - (hi << 7)); // [-64,63]
}

__device__ __forceinline__ void gl_lds16(const signed char* g, signed char* lds) {
    __builtin_amdgcn_global_load_lds(
        (const __attribute__((address_space(1))) void*)g,
        (__attribute__((address_space(3))) void*)lds, 16, 0, 0);
}

// out[m][n] = epilogue( sum_k Aop[m][k]*Bop[k][n] ); Bop in B^T layout [n][k].
// Block tile 128 x BN; WM x WN waves of 64 lanes (NTHR = WM*WN*64).
// EPI 0: outF = mu * v                   (x0; A=y planes, B=AT planes)
// EPI 1: outF = v - Yaux                 (r;  A=x planes, B=A planes)
// EPI 2: outF = replay(Zprev) - mu * v   (z;  A=r planes, B=AT planes;
//         replay(z) = |z|>=thr ? z : copysign(max(|z|-betaPrev,0), z))
template<int BN, int WM, int WN, int EPI>
__global__ __launch_bounds__(WM * WN * 64, (WM * WN == 8) ? 4 : 2)
void gemm_i8(
    const signed char* __restrict__ A1, const signed char* __restrict__ A0, int lda,
    const signed char* __restrict__ B1, const signed char* __restrict__ B0, int ldb,
    const float* __restrict__ sAv,   // per-row scale of A-operand
    const float* __restrict__ sBv,   // per-row scale of B-operand (per out col)
    const float* __restrict__ Yaux,  // EPI1: y fp32
    const float* __restrict__ Zprev, // EPI2: z_{t-1} fp32 (= outF buffer)
    const float* __restrict__ thrv,  // EPI2: per-row shrink threshold (t-1)
    const float* __restrict__ bPrev, // EPI2: &beta[t-1]
    float* __restrict__ outF,
    const float* __restrict__ muPtr, int muIdx, int K, int ldOut)
{
    constexpr int NTHR = WM * WN * 64;
    constexpr int MI   = 128 / WM / 16;   // m-frags per wave
    constexpr int NJf  = BN / WN / 16;    // n-frags per wave
    constexpr int AR   = 512 / NTHR;      // A 16B-chunk iters per plane
    constexpr int BR   = (BN * 4) / NTHR; // B 16B-chunk iters per plane
    constexpr int LPT  = 2 * (AR + BR);   // gl_lds loads per tile per thread
    constexpr int ASZ  = 128 * 64;        // one A staging buffer (bytes)
    constexpr int BSZ  = BN * 64;         // one B staging buffer (bytes)

    // staging buffers; after the K-loop, reused as fp32 epi tile [128][BN]
    // (epi tile = 128*BN*4 bytes <= 4*ASZ + 4*BSZ for BN in {64,128})
    __shared__ signed char smem[4 * ASZ + 4 * BSZ];
    signed char* const As1p = smem;                       // [2][ASZ]
    signed char* const As0p = smem + 2 * ASZ;             // [2][ASZ]
    signed char* const Bs1p = smem + 4 * ASZ;             // [2][BSZ]
    signed char* const Bs0p = smem + 4 * ASZ + 2 * BSZ;   // [2][BSZ]

    const int tid  = threadIdx.x;
    const int wid  = tid >> 6;
    const int lane = tid & 63;
    const int quad = lane >> 4;
    const int l16  = lane & 15;
    const int waveM = (wid / WN) * (MI * 16);
    const int waveN = (wid % WN) * (NJf * 16);
    const int swz   = (l16 >> 1) & 3;          // read-side XOR (rows: base%16==0)

    const int flat  = blockIdx.x + gridDim.x * blockIdx.y;
    const int mBase = (flat & 63) * 128;
    const int nBase = (flat >> 6) * BN;

    int4v accH[MI][NJf] = {};
    int4v accM[MI][NJf] = {};

    // Stage one 64-K tile into buffer b. LDS dest linear (global_load_lds
    // requirement); the global SOURCE chunk is XOR-swizzled so that the
    // ds_read below, applying the same XOR, sees logical chunk order.
    auto stage = [&](int b, int k0) {
        #pragma unroll
        for (int rr = 0; rr < AR; ++rr) {
            int c   = rr * NTHR + tid;         // 16B chunk id
            int row = c >> 2;
            int js  = (c & 3) ^ ((row >> 1) & 3);
            size_t ga = (size_t)(mBase + row) * lda + k0 + js * 16;
            size_t doff = (size_t)(b * ASZ + (rr * NTHR + wid * 64) * 16);
            gl_lds16(A1 + ga, As1p + doff);
            gl_lds16(A0 + ga, As0p + doff);
        }
        #pragma unroll
        for (int rr = 0; rr < BR; ++rr) {
            int c   = rr * NTHR + tid;
            int row = c >> 2;
            int js  = (c & 3) ^ ((row >> 1) & 3);
            size_t gb = (size_t)(nBase + row) * ldb + k0 + js * 16;
            size_t doff = (size_t)(b * BSZ + (rr * NTHR + wid * 64) * 16);
            gl_lds16(B1 + gb, Bs1p + doff);
            gl_lds16(B0 + gb, Bs0p + doff);
        }
    };

    const int KT = K >> 6;
    stage(0, 0);

    for (int kt = 0; kt < KT; ++kt) {
        const int cur = kt & 1;
        if (kt + 1 < KT) {
            stage(cur ^ 1, (kt + 1) << 6);
            // wait tile-kt's loads only; tile-(kt+1)'s LPT stay in flight
            if constexpr (LPT == 4)      asm volatile("s_waitcnt vmcnt(4)" ::: "memory");
            else if constexpr (LPT == 6) asm volatile("s_waitcnt vmcnt(6)" ::: "memory");
            else                         asm volatile("s_waitcnt vmcnt(8)" ::: "memory");
        } else {
            asm volatile("s_waitcnt vmcnt(0)" ::: "memory");
        }
        __builtin_amdgcn_s_barrier();          // raw: no vmcnt drain

        int4v a1[MI], a0[MI], b1[NJf], b0[NJf];
        #pragma unroll
        for (int i = 0; i < MI; ++i) {
            int off = (waveM + i * 16 + l16) * 64 + ((quad ^ swz) * 16);
            a1[i] = *(const int4v*)(As1p + cur * ASZ + off);
            a0[i] = *(const int4v*)(As0p + cur * ASZ + off);
        }
        #pragma unroll
        for (int j = 0; j < NJf; ++j) {
            int off = (waveN + j * 16 + l16) * 64 + ((quad ^ swz) * 16);
            b1[j] = *(const int4v*)(Bs1p + cur * BSZ + off);
            b0[j] = *(const int4v*)(Bs0p + cur * BSZ + off);
        }
        __builtin_amdgcn_s_setprio(1);
        #pragma unroll
        for (int i = 0; i < MI; ++i)
            #pragma unroll
            for (int j = 0; j < NJf; ++j) {
                accH[i][j] = __builtin_amdgcn_mfma_i32_16x16x64_i8(a1[i], b1[j], accH[i][j], 0, 0, 0);
                accM[i][j] = __builtin_amdgcn_mfma_i32_16x16x64_i8(a1[i], b0[j], accM[i][j], 0, 0, 0);
                accM[i][j] = __builtin_amdgcn_mfma_i32_16x16x64_i8(a0[i], b1[j], accM[i][j], 0, 0, 0);
            }
        __builtin_amdgcn_s_setprio(0);
        __builtin_amdgcn_s_barrier();          // reads of buf[cur] done before
                                               // next iter's stage overwrites it
    }

    // ---- epilogue: acc -> LDS tile (fragment layout), then coalesced
    //      float4 global I/O (R17). Same per-element fp32 ops -> bit-exact.
    const float mu = muPtr[muIdx];
    const float betaPrev = (EPI == 2) ? bPrev[0] : 0.f;
    float* const epi = (float*)smem;           // [128][BN]

    #pragma unroll
    for (int i = 0; i < MI; ++i) {
        #pragma unroll
        for (int j = 0; j < NJf; ++j) {
            const int lr0 = waveM + i * 16 + quad * 4;
            const int lc  = waveN + j * 16 + l16;
            const float sB = sBv[nBase + lc];
            #pragma unroll
            for (int r2 = 0; r2 < 4; ++r2) {
                const int lr = lr0 + r2;
                const float sA = sAv[mBase + lr];
                epi[lr * BN + lc] = sA * sB *
                    ((float)accH[i][j][r2] * 16384.f
                   + (float)accM[i][j][r2] * 128.f);
            }
        }
    }
    __syncthreads();

    constexpr int C4   = BN / 4;               // float4 per tile row
    constexpr int PASS = (128 * C4) / NTHR;    // = 8 for both shapes
    #pragma unroll
    for (int p = 0; p < PASS; ++p) {
        const int e  = p * NTHR + tid;
        const int lr = e / C4;
        const int c4 = e % C4;
        const int gr = mBase + lr;
        const size_t idx = (size_t)gr * ldOut + nBase + c4 * 4;
        const float4 v4 = *(const float4*)&epi[lr * BN + c4 * 4];
        float4 o;
        if constexpr (EPI == 0) {
            o.x = mu * v4.x; o.y = mu * v4.y;
            o.z = mu * v4.z; o.w = mu * v4.w;
        } else if constexpr (EPI == 1) {
            const float4 ya = *(const float4*)&Yaux[idx];
            o.x = v4.x - ya.x; o.y = v4.y - ya.y;
            o.z = v4.z - ya.z; o.w = v4.w - ya.w;
        } else {
            const float4 zp = *(const float4*)&Zprev[idx];
            const unsigned tb = __float_as_uint(thrv[gr]);
            const float zc[4] = {zp.x, zp.y, zp.z, zp.w};
            const float vc[4] = {v4.x, v4.y, v4.z, v4.w};
            float oc[4];
            #pragma unroll
            for (int k4 = 0; k4 < 4; ++k4) {
                // bit-exact shrink replay of z_{t-1} (same ops as
                // shrink_kernel: uint-bit compare, fmaxf, copysignf)
                const unsigned ab = __float_as_uint(fabsf(zc[k4]));
                float xv;
                if (ab >= tb) {
                    xv = zc[k4];
                } else {
                    xv = copysignf(
                        fmaxf(__uint_as_float(ab) - betaPrev, 0.f), zc[k4]);
                }
                oc[k4] = xv - mu * vc[k4];
            }
            o.x = oc[0]; o.y = oc[1]; o.z = oc[2]; o.w = oc[3];
        }
        *(float4*)&outF[idx] = o;
    }
}

// per-row quantization of a fp32 matrix to i8 dual planes + row scale
template<int COLS>
__global__ __launch_bounds__(256) void rowquant_kernel(
    const float* __restrict__ src,
    signed char* __restrict__ q1, signed char* __restrict__ q0,
    float* __restrict__ scale)
{
    const int wid  = threadIdx.x >> 6;
    const int lane = threadIdx.x & 63;
    const long long row = (long long)blockIdx.x * 4 + wid;
    constexpr int EP = COLS / 256;   // float4 per lane
    const float* s = src + row * COLS;

    float v[EP * 4];
    #pragma unroll
    for (int c = 0; c < EP; ++c) {
        float4 f = ((const float4*)s)[c * 64 + lane];
        v[c * 4 + 0] = f.x; v[c * 4 + 1] = f.y; v[c * 4 + 2] = f.z; v[c * 4 + 3] = f.w;
    }
    float mx = 0.f;
    #pragma unroll
    for (int i = 0; i < EP * 4; ++i) mx = fmaxf(mx, fabsf(v[i]));
    #pragma unroll
    for (int off = 32; off >= 1; off >>= 1) mx = fmaxf(mx, __shfl_xor(mx, off, 64));
    mx = fmaxf(mx, 1e-20f);
    if (lane == 0) scale[row] = mx / 16256.f;
    const float inv = 16256.f / mx;

    #pragma unroll
    for (int c = 0; c < EP; ++c) {
        size_t col = (size_t)(c * 64 + lane) * 4;
        signed char h[4], l[4];
        #pragma unroll
        for (int e = 0; e < 4; ++e) quant2(v[c * 4 + e], inv, h[e], l[e]);
        *(char4*)(q1 + row * COLS + col) = *(char4*)h;
        *(char4*)(q0 + row * COLS + col) = *(char4*)l;
    }
}

// R11/R14: one wave per row of z[.,2048]: exact k-th-largest |z| hard/soft
// threshold via scalar binary search on float bits with ballot counting +
// uniform early exit. Publishes per-row thr (for the next z-GEMM's exact
// replay), quantizes x -> i8 planes + scale (writePlanes), optionally
// writes x fp32 (writeF32, final iteration only).
__global__ __launch_bounds__(256) void shrink_kernel(
    float* __restrict__ z,
    signed char* __restrict__ X1, signed char* __restrict__ X0,
    float* __restrict__ sX, float* __restrict__ thrOut,
    const float* __restrict__ betaPtr, int tIdx, int kSel,
    int writeF32, int writePlanes)
{
    const int wid  = threadIdx.x >> 6;
    const int lane = threadIdx.x & 63;
    const long long row = (long long)blockIdx.x * 4 + wid;
    float* zr = z + row * 2048;

    float v[32];
    #pragma unroll
    for (int c = 0; c < 8; ++c) {
        float4 f = ((const float4*)zr)[c * 64 + lane];
        v[c * 4 + 0] = f.x; v[c * 4 + 1] = f.y; v[c * 4 + 2] = f.z; v[c * 4 + 3] = f.w;
    }

    if (kSel > 0) {
        const float beta = betaPtr[tIdx];
        unsigned a[32];
        #pragma unroll
        for (int i = 0; i < 32; ++i) a[i] = __float_as_uint(fabsf(v[i]));

        // invariant: cnt(>=lo) >= k, cnt(>=hi) < k. Early exit: any mid
        // with cnt(>=mid)==k classifies exactly the top-k set (identical
        // to thr = k-th largest); a tie straddling k makes cnt==k
        // unreachable -> loop runs to convergence (thr = v_k), also exact.
        unsigned lo = 0u, hi = 0x7F800000u;
        #pragma unroll 1
        for (int it = 0; it < 31; ++it) {
            const unsigned mid = (lo + hi) >> 1;
            int cnt = 0;
            #pragma unroll
            for (int i = 0; i < 32; ++i)
                cnt += (int)__popcll(__ballot(a[i] >= mid));
            if (cnt >= kSel) {
                lo = mid;
                if (cnt == kSel) break;
            } else {
                hi = mid;
            }
        }
        const unsigned thr = lo;
        if (lane == 0) thrOut[row] = __uint_as_float(thr);
        #pragma unroll
        for (int i = 0; i < 32; ++i) {
            if (a[i] < thr) {
                float av   = __uint_as_float(a[i]);
                float soft = fmaxf(av - beta, 0.f);
                v[i] = copysignf(soft, v[i]);
            }
        }
    } else {
        // no thresholding this step: replay must be identity -> thr = 0
        if (lane == 0) thrOut[row] = 0.f;
    }

    float mx = 0.f;
    #pragma unroll
    for (int i = 0; i < 32; ++i) mx = fmaxf(mx, fabsf(v[i]));
    #pragma unroll
    for (int off = 32; off >= 1; off >>= 1) mx = fmaxf(mx, __shfl_xor(mx, off, 64));
    mx = fmaxf(mx, 1e-20f);
    if (writePlanes && lane == 0) sX[row] = mx / 16256.f;
    const float inv = 16256.f / mx;

    #pragma unroll
    for (int c = 0; c < 8; ++c) {
        size_t col = (size_t)(c * 64 + lane) * 4;
        if (writePlanes) {
            signed char h[4], l[4];
            #pragma unroll
            for (int e = 0; e < 4; ++e) quant2(v[c * 4 + e], inv, h[e], l[e]);
            *(char4*)(X1 + row * 2048 + col) = *(char4*)h;
            *(char4*)(X0 + row * 2048 + col) = *(char4*)l;
        }
        if (writeF32) {
            float4 f;
            f.x = v[c * 4 + 0]; f.y = v[c * 4 + 1]; f.z = v[c * 4 + 2]; f.w = v[c * 4 + 3];
            ((float4*)zr)[c * 64 + lane] = f;
        }
    }
}

extern "C" void kernel_launch(void* const* d_in, const int* in_sizes, int n_in,
                              void* d_out, int out_size, void* d_ws, size_t ws_size,
                              hipStream_t stream)
{
    const float* y    = (const float*)d_in[0];   // [8192,512]
    const float* A    = (const float*)d_in[1];   // [512,2048]
    const float* W    = (const float*)d_in[2];   // [2048,512] == A^T
    const float* beta = (const float*)d_in[3];   // [6]
    const float* mu   = (const float*)d_in[4];   // [6]
    float* out = (float*)d_out;                  // x / z fp32, in place

    // workspace (~68 MB)
    signed char* A1q  = (signed char*)d_ws;          // [512][2048]
    signed char* A0q  = A1q  + 512 * 2048;
    signed char* AT1q = A0q  + 512 * 2048;           // [2048][512]
    signed char* AT0q = AT1q + 2048 * 512;
    signed char* y1q  = AT0q + 2048 * 512;           // [8192][512]
    signed char* y0q  = y1q  + 8192 * 512;
    signed char* x1q  = y0q  + 8192 * 512;           // [8192][2048]
    signed char* x0q  = x1q  + (size_t)8192 * 2048;
    signed char* r1q  = x0q  + (size_t)8192 * 2048;  // [8192][512]
    signed char* r0q  = r1q  + 8192 * 512;
    float* rF  = (float*)(r0q + 8192 * 512);         // [8192][512] fp32
    float* sa  = rF + (size_t)8192 * 512;            // [512]
    float* sat = sa  + 512;                          // [2048]
    float* sy  = sat + 2048;                         // [8192]
    float* sx  = sy  + 8192;                         // [8192]
    float* sr  = sx  + 8192;                         // [8192]
    float* thr = sr  + 8192;                         // [8192]

    rowquant_kernel<2048><<<128, 256, 0, stream>>>(A, A1q, A0q, sa);
    rowquant_kernel<512><<<512, 256, 0, stream>>>(W, AT1q, AT0q, sat);
    rowquant_kernel<512><<<2048, 256, 0, stream>>>(y, y1q, y0q, sy);

    // x0 = mu0 * y @ A  -> d_out fp32   (A-op = y planes, B-op = AT planes)
    gemm_i8<128, 4, 2, 0><<<dim3(16, 64), 512, 0, stream>>>(
        y1q, y0q, 512, AT1q, AT0q, 512, sy, sat,
        nullptr, nullptr, nullptr, nullptr, out, mu, 0, 512, 2048);
    // quantize x0 for GEMM use; thr=0 so the t=1 replay is identity
    shrink_kernel<<<2048, 256, 0, stream>>>(out, x1q, x0q, sx, thr, beta,
                                            0, 0, 0, 1);

    for (int t = 1; t <= 5; ++t) {
        double p = 0.012 * t; if (p > 0.12) p = 0.12;
        int kSel = (int)(p * 2048.0);   // 24,49,73,98,122

        // r = x @ A^T - y  -> rF fp32   (A-op = x planes, B-op = A planes)
        gemm_i8<64, 2, 2, 1><<<dim3(8, 64), 256, 0, stream>>>(
            x1q, x0q, 2048, A1q, A0q, 2048, sx, sa,
            y, nullptr, nullptr, nullptr, rF, mu, t, 2048, 512);
        // quantize r per-row
        rowquant_kernel<512><<<2048, 256, 0, stream>>>(rF, r1q, r0q, sr);

        // z = replay(z_{t-1}) - mu_t * (r @ A)  in place over d_out
        // (Zprev = out read via const __restrict__, R15's measured-fast form)
        gemm_i8<128, 4, 2, 2><<<dim3(16, 64), 512, 0, stream>>>(
            r1q, r0q, 512, AT1q, AT0q, 512, sr, sat,
            nullptr, out, thr, beta + (t - 1), out, mu, t, 512, 2048);

        // x = shrink(z): t<5 -> planes+thr only; t=5 -> fp32 output only
        shrink_kernel<<<2048, 256, 0, stream>>>(out, x1q, x0q, sx, thr, beta,
                                                t, kSel, t == 5 ? 1 : 0,
                                                t < 5 ? 1 : 0);
    }
}